// Round 3
// baseline (115.021 us; speedup 1.0000x reference)
//
#include <hip/hip_runtime.h>
#include <hip/hip_bf16.h>

// Problem constants
#define B_SZ   16
#define V_IN   1024
#define V_OUT  4096
#define C_IN   128
#define C_OUT  256
#define K_NB   18
#define NNZ    16384
#define K_GEMM (K_NB * C_IN)   // 2304
#define BK     64
#define NKT    (K_GEMM / BK)   // 36

typedef __attribute__((ext_vector_type(8))) short bf16x8;   // 8 bf16 = 4 VGPRs
typedef __attribute__((ext_vector_type(4))) float f32x4;

#define GLOAD16(src, dst) __builtin_amdgcn_global_load_lds( \
    (const __attribute__((address_space(1))) unsigned int*)(src), \
    (__attribute__((address_space(3))) unsigned int*)(dst), 16, 0, 0)

// ---------------- CSR build ----------------
__global__ void zero_counts_kernel(int* counts) {
    int i = blockIdx.x * blockDim.x + threadIdx.x;
    if (i < V_OUT) counts[i] = 0;
}

__global__ void hist_kernel(const int* __restrict__ rows, int* counts) {
    int n = blockIdx.x * blockDim.x + threadIdx.x;
    if (n < NNZ) atomicAdd(&counts[rows[n]], 1);
}

__global__ void scan_kernel(const int* __restrict__ counts, int* offsets, int* cursor) {
    __shared__ int s[1024];
    int t = threadIdx.x;
    int base = t * 4;
    int c0 = counts[base], c1 = counts[base + 1], c2 = counts[base + 2], c3 = counts[base + 3];
    int tot = c0 + c1 + c2 + c3;
    s[t] = tot;
    __syncthreads();
    for (int d = 1; d < 1024; d <<= 1) {
        int v = (t >= d) ? s[t - d] : 0;
        __syncthreads();
        s[t] += v;
        __syncthreads();
    }
    int excl = s[t] - tot;
    offsets[base]     = excl;
    offsets[base + 1] = excl + c0;
    offsets[base + 2] = excl + c0 + c1;
    offsets[base + 3] = excl + c0 + c1 + c2;
    cursor[base]     = excl;
    cursor[base + 1] = excl + c0;
    cursor[base + 2] = excl + c0 + c1;
    cursor[base + 3] = excl + c0 + c1 + c2;
    if (t == 1023) offsets[V_OUT] = s[1023];
}

__global__ void fill_kernel(const int* __restrict__ rows, int* cursor, int* perm) {
    int n = blockIdx.x * blockDim.x + threadIdx.x;
    if (n < NNZ) {
        int r = rows[n];
        int pos = atomicAdd(&cursor[r], 1);
        perm[pos] = n;
    }
}

// ---------------- pooling: one block per out-row, 16 batch accumulators ----------------
__global__ __launch_bounds__(128) void pool_kernel(
    const float* __restrict__ x, const float* __restrict__ vals,
    const int* __restrict__ cols, const int* __restrict__ offsets,
    const int* __restrict__ perm, __hip_bfloat16* __restrict__ pool) {
    int r = blockIdx.x;
    int c = threadIdx.x;
    int j0 = offsets[r], j1 = offsets[r + 1];
    float acc[B_SZ];
#pragma unroll
    for (int b = 0; b < B_SZ; ++b) acc[b] = 0.f;
    for (int j = j0; j < j1; ++j) {
        int n = perm[j];
        float v = vals[n];
        const float* xp = x + (size_t)cols[n] * C_IN + c;
#pragma unroll
        for (int b = 0; b < B_SZ; ++b) acc[b] += v * xp[(size_t)b * V_IN * C_IN];
    }
#pragma unroll
    for (int b = 0; b < B_SZ; ++b)
        pool[((size_t)b * V_OUT + r) * C_IN + c] = __float2bfloat16(acc[b]);
}

// ---------------- combined weight, pre-swizzled per-K-tile LDS image ----------------
__global__ void wcomb_kernel(const float* __restrict__ W1, const float* __restrict__ Wd3,
                             const float* __restrict__ W2d3, const float* __restrict__ Wf,
                             __hip_bfloat16* __restrict__ wTs) {
    int idx = blockIdx.x * blockDim.x + threadIdx.x;       // 0 .. 36*16384-1
    if (idx >= NKT * 16384) return;
    int kt = idx >> 14;
    int c  = (idx >> 3) & 2047;
    int e  = idx & 7;
    int nrow  = c >> 3;
    int kslot = (c & 7) << 4;
    int kb = kslot ^ ((nrow & 7) << 4);
    int r  = kt * 64 + (kb >> 1) + e;    // global k, 0..2303
    int col = nrow;
    float v;
    if (col < 128)      v = Wf[r * 128 + col];
    else if (col < 192) v = (r < 1536) ? W2d3[r * 64 + (col - 128)] : 0.f;
    else                v = (r < 768)  ? Wd3[r * 64 + (col - 192)]  : 0.f;
    if (r < 128) v += W1[r * 256 + col];
    wTs[idx] = __float2bfloat16(v);
}

__global__ void bias_kernel(const float* __restrict__ b1, const float* __restrict__ bd3,
                            const float* __restrict__ b2d3, const float* __restrict__ bf,
                            float* __restrict__ bias) {
    int c = threadIdx.x;
    float v = b1[c];
    if (c < 128)      v += bf[c];
    else if (c < 192) v += b2d3[c - 128];
    else              v += bd3[c - 192];
    bias[c] = v;
}

// ---------------- gathered GEMM: 256x256 tile, 4-phase counted-vmcnt schedule ----------------
__global__ __launch_bounds__(512, 2) void gemm_kernel(
    const __hip_bfloat16* __restrict__ pool,    // [16][4096][128] bf16
    const __hip_bfloat16* __restrict__ wTs,     // [36][16384] bf16, pre-swizzled K-tile images
    const float* __restrict__ bias,             // [256]
    const int* __restrict__ spiral,             // [4096][18]
    float* __restrict__ out)                    // [16][4096][256] f32
{
    // LDS: A slots @0,32768 ; B slots @65536,98304 ; spiral cache @131072 (18432B)
    __shared__ __align__(16) char smem[149504];
    int* spl = (int*)(smem + 131072);

    const int tid  = threadIdx.x;
    const int lane = tid & 63;
    const int wid  = tid >> 6;
    const int wm   = (wid >> 2) << 7;     // 0 / 128
    const int wn   = (wid & 3) << 6;      // 0,64,128,192

    const int bid = blockIdx.x;
    const int bm  = ((bid & 7) << 5) + (bid >> 3);   // bijective XCD swizzle (256 = 8*32)
    const int b   = bm >> 4;                          // batch
    const int v0  = (bm & 15) << 8;                   // m-tile origin within batch

    // cache this block's spiral rows in LDS: 256 rows x 18
    for (int i = tid; i < 256 * K_NB; i += 512) spl[i] = spiral[v0 * K_NB + i];
    // drain everything (clean vmcnt baseline), then raw barrier
    asm volatile("s_waitcnt vmcnt(0) lgkmcnt(0)" ::: "memory");
    __builtin_amdgcn_s_barrier();

    const char* poolBytes = (const char*)(pool + (size_t)b * V_OUT * C_IN);
    const char* wTsBytes  = (const char*)wTs;
    const int tg3 = tid >> 3;                              // 0..63 (row-in-64 group)
    const int sb  = ((tid & 7) << 4) ^ ((tg3 & 7) << 4);   // inverse-swizzled col byte

    auto stageA = [&](int kt) {          // 4 vmem loads
        const int j   = kt >> 1;
        const int c0b = (kt & 1) << 7;
        char* dst = smem + ((kt & 1) << 15);
#pragma unroll
        for (int ch = 0; ch < 4; ++ch) {
            int sidx = spl[(ch * 64 + tg3) * K_NB + j];
            GLOAD16(poolBytes + ((size_t)sidx << 8) + (c0b + sb),
                    dst + ((ch << 9) + tid) * 16);
        }
    };
    auto stageB = [&](int kt) {          // 4 vmem loads
        const char* src = wTsBytes + ((size_t)kt << 15) + tid * 16;
        char* dst = smem + 65536 + ((kt & 1) << 15);
#pragma unroll
        for (int ch = 0; ch < 4; ++ch)
            GLOAD16(src + (ch << 13), dst + (ch << 13) + tid * 16);
    };

    // per-lane fragment-read constants
    const int l15   = lane & 15;
    const int swm   = (lane & 7) << 4;          // row&7 == lane&7 for all frag rows
    const int klane = (lane >> 4) << 4;         // 0,16,32,48
    const int aRow  = (wm + l15) << 7;          // byte offset of lane's A row base
    const int bRow  = (wn + l15) << 7;

    f32x4 acc[8][4] = {};

    // prologue: A(0), B(0), A(1) in flight; guarantee tile-0 data before loop
    stageA(0);
    stageB(0);
    stageA(1);
    asm volatile("s_waitcnt vmcnt(4)" ::: "memory");   // A(0),B(0) landed; A(1) in flight
    __builtin_amdgcn_s_barrier();

    for (int T = 0; T < NKT; ++T) {
        const int s = T & 1;
        const char* As = smem + (s << 15);
        const char* Bs = smem + 65536 + (s << 15);
        bf16x8 a[8], b0, b1, b2, b3;

        // ================ P1: ks=0, ni 0,1 ================
        if (T + 1 < NKT) stageB(T + 1);
#pragma unroll
        for (int mi = 0; mi < 8; ++mi)
            a[mi] = *(const bf16x8*)(As + aRow + (mi << 11) + ((0 + klane) ^ swm));
        b0 = *(const bf16x8*)(Bs + bRow + (0 << 11) + ((0 + klane) ^ swm));
        b1 = *(const bf16x8*)(Bs + bRow + (1 << 11) + ((0 + klane) ^ swm));
        __builtin_amdgcn_s_barrier();                       // bar_a
        asm volatile("s_waitcnt lgkmcnt(0)" ::: "memory");
        __builtin_amdgcn_sched_barrier(0);
        __builtin_amdgcn_s_setprio(1);
#pragma unroll
        for (int mi = 0; mi < 8; ++mi) {
            acc[mi][0] = __builtin_amdgcn_mfma_f32_16x16x32_bf16(a[mi], b0, acc[mi][0], 0, 0, 0);
            acc[mi][1] = __builtin_amdgcn_mfma_f32_16x16x32_bf16(a[mi], b1, acc[mi][1], 0, 0, 0);
        }
        __builtin_amdgcn_s_setprio(0);

        // ================ P2: ks=0, ni 2,3 ================
        b2 = *(const bf16x8*)(Bs + bRow + (2 << 11) + ((0 + klane) ^ swm));
        b3 = *(const bf16x8*)(Bs + bRow + (3 << 11) + ((0 + klane) ^ swm));
        __builtin_amdgcn_s_barrier();                       // bar_a
        asm volatile("s_waitcnt lgkmcnt(0)" ::: "memory");
        __builtin_amdgcn_sched_barrier(0);
        __builtin_amdgcn_s_setprio(1);
#pragma unroll
        for (int mi = 0; mi < 8; ++mi) {
            acc[mi][2] = __builtin_amdgcn_mfma_f32_16x16x32_bf16(a[mi], b2, acc[mi][2], 0, 0, 0);
            acc[mi][3] = __builtin_amdgcn_mfma_f32_16x16x32_bf16(a[mi], b3, acc[mi][3], 0, 0, 0);
        }
        __builtin_amdgcn_s_setprio(0);

        // ================ P3: ks=1, ni 0,1 ================
#pragma unroll
        for (int mi = 0; mi < 8; ++mi)
            a[mi] = *(const bf16x8*)(As + aRow + (mi << 11) + ((64 + klane) ^ swm));
        b0 = *(const bf16x8*)(Bs + bRow + (0 << 11) + ((64 + klane) ^ swm));
        b1 = *(const bf16x8*)(Bs + bRow + (1 << 11) + ((64 + klane) ^ swm));
        __builtin_amdgcn_s_barrier();                       // bar_a
        asm volatile("s_waitcnt lgkmcnt(0)" ::: "memory");
        __builtin_amdgcn_sched_barrier(0);
        __builtin_amdgcn_s_setprio(1);
#pragma unroll
        for (int mi = 0; mi < 8; ++mi) {
            acc[mi][0] = __builtin_amdgcn_mfma_f32_16x16x32_bf16(a[mi], b0, acc[mi][0], 0, 0, 0);
            acc[mi][1] = __builtin_amdgcn_mfma_f32_16x16x32_bf16(a[mi], b1, acc[mi][1], 0, 0, 0);
        }
        __builtin_amdgcn_s_setprio(0);
        __builtin_amdgcn_s_barrier();                       // bar_b: A-slot reads complete
        __builtin_amdgcn_sched_barrier(0);

        // ================ P4: ks=1, ni 2,3 ================
        b2 = *(const bf16x8*)(Bs + bRow + (2 << 11) + ((64 + klane) ^ swm));
        b3 = *(const bf16x8*)(Bs + bRow + (3 << 11) + ((64 + klane) ^ swm));
        if (T + 2 < NKT) {
            stageA(T + 2);                                  // safe: A-slot reads done (bar_b P3)
            asm volatile("s_waitcnt vmcnt(4)" ::: "memory");  // B(T+1),A(T+1) landed
        } else {
            asm volatile("s_waitcnt vmcnt(0)" ::: "memory");  // tail drain
        }
        __builtin_amdgcn_s_barrier();                       // bar_a
        asm volatile("s_waitcnt lgkmcnt(0)" ::: "memory");
        __builtin_amdgcn_sched_barrier(0);
        __builtin_amdgcn_s_setprio(1);
#pragma unroll
        for (int mi = 0; mi < 8; ++mi) {
            acc[mi][2] = __builtin_amdgcn_mfma_f32_16x16x32_bf16(a[mi], b2, acc[mi][2], 0, 0, 0);
            acc[mi][3] = __builtin_amdgcn_mfma_f32_16x16x32_bf16(a[mi], b3, acc[mi][3], 0, 0, 0);
        }
        __builtin_amdgcn_s_setprio(0);
        __builtin_amdgcn_s_barrier();                       // bar_b: B-slot reads complete
        __builtin_amdgcn_sched_barrier(0);
    }

    // epilogue: +bias, relu, store f32
#pragma unroll
    for (int ni = 0; ni < 4; ++ni) {
        int col = wn + ni * 16 + l15;
        float bz = bias[col];
#pragma unroll
        for (int mi = 0; mi < 8; ++mi) {
            int row0 = v0 + wm + mi * 16 + ((lane >> 4) << 2);
#pragma unroll
            for (int r4 = 0; r4 < 4; ++r4) {
                float v = acc[mi][ni][r4] + bz;
                out[((size_t)(b * V_OUT + row0 + r4)) * C_OUT + col] = v > 0.f ? v : 0.f;
            }
        }
    }
}

extern "C" void kernel_launch(void* const* d_in, const int* in_sizes, int n_in,
                              void* d_out, int out_size, void* d_ws, size_t ws_size,
                              hipStream_t stream) {
    const float* x     = (const float*)d_in[0];
    const float* vals  = (const float*)d_in[1];
    const float* W1    = (const float*)d_in[2];
    const float* b1    = (const float*)d_in[3];
    const float* Wd3   = (const float*)d_in[4];
    const float* bd3   = (const float*)d_in[5];
    const float* W2d3  = (const float*)d_in[6];
    const float* b2d3  = (const float*)d_in[7];
    const float* Wf    = (const float*)d_in[8];
    const float* bf    = (const float*)d_in[9];
    const int*   rows  = (const int*)d_in[10];
    const int*   cols  = (const int*)d_in[11];
    const int*   spiral= (const int*)d_in[12];
    float* out = (float*)d_out;

    // workspace layout
    char* ws = (char*)d_ws;
    __hip_bfloat16* pool = (__hip_bfloat16*)ws;                              // 16,777,216 B
    __hip_bfloat16* wTs  = (__hip_bfloat16*)(ws + 16777216);                 //  1,179,648 B
    float* bias          = (float*)(ws + 16777216 + 1179648);                //      1,024 B
    int*   counts        = (int*)(ws + 16777216 + 1179648 + 1024);
    int*   offsets       = counts + V_OUT;          // V_OUT+1 ints
    int*   cursor        = offsets + V_OUT + 4;     // padded
    int*   perm          = cursor + V_OUT;

    zero_counts_kernel<<<(V_OUT + 255) / 256, 256, 0, stream>>>(counts);
    hist_kernel<<<NNZ / 256, 256, 0, stream>>>(rows, counts);
    scan_kernel<<<1, 1024, 0, stream>>>(counts, offsets, cursor);
    fill_kernel<<<NNZ / 256, 256, 0, stream>>>(rows, cursor, perm);
    pool_kernel<<<V_OUT, C_IN, 0, stream>>>(x, vals, cols, offsets, perm, pool);
    wcomb_kernel<<<(NKT * 16384 + 255) / 256, 256, 0, stream>>>(W1, Wd3, W2d3, Wf, wTs);
    bias_kernel<<<1, C_OUT, 0, stream>>>(b1, bd3, b2d3, bf, bias);
    gemm_kernel<<<256, 512, 0, stream>>>(pool, wTs, bias, spiral, out);
}

// Round 4
// 108.844 us; speedup vs baseline: 1.0568x; 1.0568x over previous
//
#include <hip/hip_runtime.h>
#include <hip/hip_bf16.h>

// Problem constants
#define B_SZ   16
#define V_IN   1024
#define V_OUT  4096
#define C_IN   128
#define C_OUT  256
#define K_NB   18
#define NNZ    16384
#define K_GEMM (K_NB * C_IN)   // 2304
#define BK     64
#define NKT    (K_GEMM / BK)   // 36

typedef __attribute__((ext_vector_type(8))) short bf16x8;   // 8 bf16 = 4 VGPRs
typedef __attribute__((ext_vector_type(4))) float f32x4;

#define GLOAD16(src, dst) __builtin_amdgcn_global_load_lds( \
    (const __attribute__((address_space(1))) unsigned int*)(src), \
    (__attribute__((address_space(3))) unsigned int*)(dst), 16, 0, 0)

// ---------------- CSR build ----------------
__global__ void hist_kernel(const int* __restrict__ rows, int* counts) {
    int n = blockIdx.x * blockDim.x + threadIdx.x;
    if (n < NNZ) atomicAdd(&counts[rows[n]], 1);
}

// 1024 threads, shfl-based scan of 4096 counts (4 per thread), 1 barrier
__global__ void scan_kernel(const int* __restrict__ counts, int* offsets, int* cursor) {
    __shared__ int wsum[16];
    int t = threadIdx.x;
    int lane = t & 63, wid = t >> 6;
    int base4 = t * 4;
    int c0 = counts[base4], c1 = counts[base4 + 1], c2 = counts[base4 + 2], c3 = counts[base4 + 3];
    int tot = c0 + c1 + c2 + c3;
    int v = tot;
#pragma unroll
    for (int d = 1; d < 64; d <<= 1) {
        int u = __shfl_up(v, d);
        if (lane >= d) v += u;
    }
    if (lane == 63) wsum[wid] = v;
    __syncthreads();
    int wbase = 0;
#pragma unroll
    for (int w = 0; w < 16; ++w) wbase += (w < wid) ? wsum[w] : 0;
    int incl = wbase + v;
    int excl = incl - tot;
    offsets[base4]     = excl;
    offsets[base4 + 1] = excl + c0;
    offsets[base4 + 2] = excl + c0 + c1;
    offsets[base4 + 3] = excl + c0 + c1 + c2;
    cursor[base4]     = excl;
    cursor[base4 + 1] = excl + c0;
    cursor[base4 + 2] = excl + c0 + c1;
    cursor[base4 + 3] = excl + c0 + c1 + c2;
    if (t == 1023) offsets[V_OUT] = incl;
}

__global__ void fill_kernel(const int* __restrict__ rows, int* cursor, int* perm) {
    int n = blockIdx.x * blockDim.x + threadIdx.x;
    if (n < NNZ) {
        int r = rows[n];
        int pos = atomicAdd(&cursor[r], 1);
        perm[pos] = n;
    }
}

// ---------------- pooling: one block per out-row, 16 batch accumulators ----------------
__global__ __launch_bounds__(128) void pool_kernel(
    const float* __restrict__ x, const float* __restrict__ vals,
    const int* __restrict__ cols, const int* __restrict__ offsets,
    const int* __restrict__ perm, __hip_bfloat16* __restrict__ pool) {
    int r = blockIdx.x;
    int c = threadIdx.x;
    int j0 = offsets[r], j1 = offsets[r + 1];
    float acc[B_SZ];
#pragma unroll
    for (int b = 0; b < B_SZ; ++b) acc[b] = 0.f;
    for (int j = j0; j < j1; ++j) {
        int n = perm[j];
        float v = vals[n];
        const float* xp = x + (size_t)cols[n] * C_IN + c;
#pragma unroll
        for (int b = 0; b < B_SZ; ++b) acc[b] += v * xp[(size_t)b * V_IN * C_IN];
    }
#pragma unroll
    for (int b = 0; b < B_SZ; ++b)
        pool[((size_t)b * V_OUT + r) * C_IN + c] = __float2bfloat16(acc[b]);
}

// ---------------- combined weight (pre-swizzled per-K-tile LDS image) + bias ----------------
__global__ void wcomb_kernel(const float* __restrict__ W1, const float* __restrict__ Wd3,
                             const float* __restrict__ W2d3, const float* __restrict__ Wf,
                             const float* __restrict__ b1, const float* __restrict__ bd3,
                             const float* __restrict__ b2d3, const float* __restrict__ bf,
                             __hip_bfloat16* __restrict__ wTs, float* __restrict__ bias) {
    int idx = blockIdx.x * blockDim.x + threadIdx.x;
    if (idx >= NKT * 16384) {
        int c = idx - NKT * 16384;
        if (c < C_OUT) {
            float v = b1[c];
            if (c < 128)      v += bf[c];
            else if (c < 192) v += b2d3[c - 128];
            else              v += bd3[c - 192];
            bias[c] = v;
        }
        return;
    }
    int kt = idx >> 14;
    int c  = (idx >> 3) & 2047;
    int e  = idx & 7;
    int nrow  = c >> 3;
    int kslot = (c & 7) << 4;
    int kb = kslot ^ ((nrow & 7) << 4);
    int r  = kt * 64 + (kb >> 1) + e;    // global k, 0..2303
    int col = nrow;
    float v;
    if (col < 128)      v = Wf[r * 128 + col];
    else if (col < 192) v = (r < 1536) ? W2d3[r * 64 + (col - 128)] : 0.f;
    else                v = (r < 768)  ? Wd3[r * 64 + (col - 192)]  : 0.f;
    if (r < 128) v += W1[r * 256 + col];
    wTs[idx] = __float2bfloat16(v);
}

// ---------------- gathered GEMM: 256x256 tile, counted-vmcnt, per-quadrant K-skip ----------------
__global__ __launch_bounds__(512, 2) void gemm_kernel(
    const __hip_bfloat16* __restrict__ pool,    // [16][4096][128] bf16
    const __hip_bfloat16* __restrict__ wTs,     // [36][16384] bf16, pre-swizzled K-tile images
    const float* __restrict__ bias,             // [256]
    const int* __restrict__ spiral,             // [4096][18]
    float* __restrict__ out)                    // [16][4096][256] f32
{
    // LDS: A slots @0,32768 ; B slots @65536,98304 ; spiral cache @131072 (18432B)
    __shared__ __align__(16) char smem[149504];
    int* spl = (int*)(smem + 131072);

    const int tid  = threadIdx.x;
    const int lane = tid & 63;
    const int wid  = tid >> 6;
    const int wm   = (wid >> 2) << 7;     // 0 / 128
    const int wn   = (wid & 3) << 6;      // 0,64,128,192
    const int q    = wid & 3;
    // cols 128..191 have zero weights for k>=1536 (kt>=24); cols 192..255 for k>=768 (kt>=12)
    const int myNKT = (q == 3) ? 12 : ((q == 2) ? 24 : NKT);

    const int bid = blockIdx.x;
    const int bm  = ((bid & 7) << 5) + (bid >> 3);   // bijective XCD swizzle (256 = 8*32)
    const int b   = bm >> 4;                          // batch
    const int v0  = (bm & 15) << 8;                   // m-tile origin within batch

    // cache this block's spiral rows in LDS: 256 rows x 18
    for (int i = tid; i < 256 * K_NB; i += 512) spl[i] = spiral[v0 * K_NB + i];
    asm volatile("s_waitcnt vmcnt(0) lgkmcnt(0)" ::: "memory");
    __builtin_amdgcn_s_barrier();

    const char* poolBytes = (const char*)(pool + (size_t)b * V_OUT * C_IN);
    const char* wTsBytes  = (const char*)wTs;
    const int tg3 = tid >> 3;                              // 0..63 (row-in-64 group)
    const int sb  = ((tid & 7) << 4) ^ ((tg3 & 7) << 4);   // inverse-swizzled col byte

    auto stageA = [&](int kt) {          // 4 vmem loads
        const int j   = kt >> 1;
        const int c0b = (kt & 1) << 7;
        char* dst = smem + ((kt & 1) << 15);
#pragma unroll
        for (int ch = 0; ch < 4; ++ch) {
            int sidx = spl[(ch * 64 + tg3) * K_NB + j];
            GLOAD16(poolBytes + ((size_t)sidx << 8) + (c0b + sb),
                    dst + ((ch << 9) + tid) * 16);
        }
    };
    auto stageB = [&](int kt) {          // 4 vmem loads
        const char* src = wTsBytes + ((size_t)kt << 15) + tid * 16;
        char* dst = smem + 65536 + ((kt & 1) << 15);
#pragma unroll
        for (int ch = 0; ch < 4; ++ch)
            GLOAD16(src + (ch << 13), dst + (ch << 13) + tid * 16);
    };

    // per-lane fragment-read constants
    const int l15   = lane & 15;
    const int swm   = (lane & 7) << 4;          // row&7 == lane&7 for all frag rows
    const int klane = (lane >> 4) << 4;         // 0,16,32,48
    const int aRow  = (wm + l15) << 7;          // byte offset of lane's A row base
    const int bRow  = (wn + l15) << 7;

    f32x4 acc[8][4] = {};

    stageA(0);
    stageB(0);

#pragma unroll 2
    for (int kt = 0; kt < NKT; ++kt) {
        const int s = kt & 1;
        const char* As = smem + (s << 15);
        const char* Bs = smem + 65536 + (s << 15);

        if (kt + 1 < NKT) {
            stageA(kt + 1);
            asm volatile("s_waitcnt vmcnt(4)" ::: "memory");   // A(kt),B(kt) landed
        } else {
            asm volatile("s_waitcnt vmcnt(0)" ::: "memory");
        }
        __builtin_amdgcn_s_barrier();
        __builtin_amdgcn_sched_barrier(0);

        const bool act = kt < myNKT;
        bf16x8 a[8], b0, b1, b2, b3;

        if (act) {
            // ---- ks=0 ----
#pragma unroll
            for (int mi = 0; mi < 8; ++mi)
                a[mi] = *(const bf16x8*)(As + aRow + (mi << 11) + ((0 + klane) ^ swm));
            b0 = *(const bf16x8*)(Bs + bRow + (0 << 11) + ((0 + klane) ^ swm));
            b1 = *(const bf16x8*)(Bs + bRow + (1 << 11) + ((0 + klane) ^ swm));
            __builtin_amdgcn_s_setprio(1);
#pragma unroll
            for (int mi = 0; mi < 8; ++mi) {
                acc[mi][0] = __builtin_amdgcn_mfma_f32_16x16x32_bf16(a[mi], b0, acc[mi][0], 0, 0, 0);
                acc[mi][1] = __builtin_amdgcn_mfma_f32_16x16x32_bf16(a[mi], b1, acc[mi][1], 0, 0, 0);
            }
            __builtin_amdgcn_s_setprio(0);
            b2 = *(const bf16x8*)(Bs + bRow + (2 << 11) + ((0 + klane) ^ swm));
            b3 = *(const bf16x8*)(Bs + bRow + (3 << 11) + ((0 + klane) ^ swm));
            __builtin_amdgcn_s_setprio(1);
#pragma unroll
            for (int mi = 0; mi < 8; ++mi) {
                acc[mi][2] = __builtin_amdgcn_mfma_f32_16x16x32_bf16(a[mi], b2, acc[mi][2], 0, 0, 0);
                acc[mi][3] = __builtin_amdgcn_mfma_f32_16x16x32_bf16(a[mi], b3, acc[mi][3], 0, 0, 0);
            }
            __builtin_amdgcn_s_setprio(0);
        }

        if (kt + 1 < NKT) stageB(kt + 1);

        if (act) {
            // ---- ks=1 ----
#pragma unroll
            for (int mi = 0; mi < 8; ++mi)
                a[mi] = *(const bf16x8*)(As + aRow + (mi << 11) + ((64 + klane) ^ swm));
            b0 = *(const bf16x8*)(Bs + bRow + (0 << 11) + ((64 + klane) ^ swm));
            b1 = *(const bf16x8*)(Bs + bRow + (1 << 11) + ((64 + klane) ^ swm));
            __builtin_amdgcn_s_setprio(1);
#pragma unroll
            for (int mi = 0; mi < 8; ++mi) {
                acc[mi][0] = __builtin_amdgcn_mfma_f32_16x16x32_bf16(a[mi], b0, acc[mi][0], 0, 0, 0);
                acc[mi][1] = __builtin_amdgcn_mfma_f32_16x16x32_bf16(a[mi], b1, acc[mi][1], 0, 0, 0);
            }
            __builtin_amdgcn_s_setprio(0);
            b2 = *(const bf16x8*)(Bs + bRow + (2 << 11) + ((64 + klane) ^ swm));
            b3 = *(const bf16x8*)(Bs + bRow + (3 << 11) + ((64 + klane) ^ swm));
            __builtin_amdgcn_s_setprio(1);
#pragma unroll
            for (int mi = 0; mi < 8; ++mi) {
                acc[mi][2] = __builtin_amdgcn_mfma_f32_16x16x32_bf16(a[mi], b2, acc[mi][2], 0, 0, 0);
                acc[mi][3] = __builtin_amdgcn_mfma_f32_16x16x32_bf16(a[mi], b3, acc[mi][3], 0, 0, 0);
            }
            __builtin_amdgcn_s_setprio(0);
        }

        __builtin_amdgcn_s_barrier();        // end of K-tile: slot reads complete
        __builtin_amdgcn_sched_barrier(0);
    }

    // epilogue: +bias, relu, store f32
#pragma unroll
    for (int ni = 0; ni < 4; ++ni) {
        int col = wn + ni * 16 + l15;
        float bz = bias[col];
#pragma unroll
        for (int mi = 0; mi < 8; ++mi) {
            int row0 = v0 + wm + mi * 16 + ((lane >> 4) << 2);
#pragma unroll
            for (int r4 = 0; r4 < 4; ++r4) {
                float v = acc[mi][ni][r4] + bz;
                out[((size_t)(b * V_OUT + row0 + r4)) * C_OUT + col] = v > 0.f ? v : 0.f;
            }
        }
    }
}

extern "C" void kernel_launch(void* const* d_in, const int* in_sizes, int n_in,
                              void* d_out, int out_size, void* d_ws, size_t ws_size,
                              hipStream_t stream) {
    const float* x     = (const float*)d_in[0];
    const float* vals  = (const float*)d_in[1];
    const float* W1    = (const float*)d_in[2];
    const float* b1    = (const float*)d_in[3];
    const float* Wd3   = (const float*)d_in[4];
    const float* bd3   = (const float*)d_in[5];
    const float* W2d3  = (const float*)d_in[6];
    const float* b2d3  = (const float*)d_in[7];
    const float* Wf    = (const float*)d_in[8];
    const float* bf    = (const float*)d_in[9];
    const int*   rows  = (const int*)d_in[10];
    const int*   cols  = (const int*)d_in[11];
    const int*   spiral= (const int*)d_in[12];
    float* out = (float*)d_out;

    // workspace layout
    char* ws = (char*)d_ws;
    __hip_bfloat16* pool = (__hip_bfloat16*)ws;                              // 16,777,216 B
    __hip_bfloat16* wTs  = (__hip_bfloat16*)(ws + 16777216);                 //  1,179,648 B
    float* bias          = (float*)(ws + 16777216 + 1179648);                //      1,024 B
    int*   counts        = (int*)(ws + 16777216 + 1179648 + 1024);
    int*   offsets       = counts + V_OUT;          // V_OUT+1 ints
    int*   cursor        = offsets + V_OUT + 4;     // padded
    int*   perm          = cursor + V_OUT;

    hipMemsetAsync(counts, 0, V_OUT * sizeof(int), stream);
    hist_kernel<<<NNZ / 256, 256, 0, stream>>>(rows, counts);
    scan_kernel<<<1, 1024, 0, stream>>>(counts, offsets, cursor);
    fill_kernel<<<NNZ / 256, 256, 0, stream>>>(rows, cursor, perm);
    pool_kernel<<<V_OUT, C_IN, 0, stream>>>(x, vals, cols, offsets, perm, pool);
    wcomb_kernel<<<(NKT * 16384 + C_OUT + 255) / 256, 256, 0, stream>>>(
        W1, Wd3, W2d3, Wf, b1, bd3, b2d3, bf, wTs, bias);
    gemm_kernel<<<256, 512, 0, stream>>>(pool, wTs, bias, spiral, out);
}

// Round 5
// 103.868 us; speedup vs baseline: 1.1074x; 1.0479x over previous
//
#include <hip/hip_runtime.h>
#include <hip/hip_bf16.h>

// Problem constants
#define B_SZ   16
#define V_IN   1024
#define V_OUT  4096
#define C_IN   128
#define C_OUT  256
#define K_NB   18
#define NNZ    16384
#define K_GEMM (K_NB * C_IN)   // 2304
#define BK     64
#define NKT    (K_GEMM / BK)   // 36

typedef __attribute__((ext_vector_type(8))) short bf16x8;   // 8 bf16 = 4 VGPRs
typedef __attribute__((ext_vector_type(4))) float f32x4;

#define GLOAD16(src, dst) __builtin_amdgcn_global_load_lds( \
    (const __attribute__((address_space(1))) unsigned int*)(src), \
    (__attribute__((address_space(3))) unsigned int*)(dst), 16, 0, 0)

// ---------------- CSR build ----------------
__global__ void hist_kernel(const int* __restrict__ rows, int* counts) {
    int n = blockIdx.x * blockDim.x + threadIdx.x;
    if (n < NNZ) atomicAdd(&counts[rows[n]], 1);
}

// 1024 threads, shfl-based scan of 4096 counts (4 per thread), 1 barrier
__global__ void scan_kernel(const int* __restrict__ counts, int* offsets, int* cursor) {
    __shared__ int wsum[16];
    int t = threadIdx.x;
    int lane = t & 63, wid = t >> 6;
    int base4 = t * 4;
    int c0 = counts[base4], c1 = counts[base4 + 1], c2 = counts[base4 + 2], c3 = counts[base4 + 3];
    int tot = c0 + c1 + c2 + c3;
    int v = tot;
#pragma unroll
    for (int d = 1; d < 64; d <<= 1) {
        int u = __shfl_up(v, d);
        if (lane >= d) v += u;
    }
    if (lane == 63) wsum[wid] = v;
    __syncthreads();
    int wbase = 0;
#pragma unroll
    for (int w = 0; w < 16; ++w) wbase += (w < wid) ? wsum[w] : 0;
    int incl = wbase + v;
    int excl = incl - tot;
    offsets[base4]     = excl;
    offsets[base4 + 1] = excl + c0;
    offsets[base4 + 2] = excl + c0 + c1;
    offsets[base4 + 3] = excl + c0 + c1 + c2;
    cursor[base4]     = excl;
    cursor[base4 + 1] = excl + c0;
    cursor[base4 + 2] = excl + c0 + c1;
    cursor[base4 + 3] = excl + c0 + c1 + c2;
    if (t == 1023) offsets[V_OUT] = incl;
}

__global__ void fill_kernel(const int* __restrict__ rows, int* cursor, int* perm) {
    int n = blockIdx.x * blockDim.x + threadIdx.x;
    if (n < NNZ) {
        int r = rows[n];
        int pos = atomicAdd(&cursor[r], 1);
        perm[pos] = n;
    }
}

// ---------------- pooling: one block per out-row, 16 batch accumulators ----------------
__global__ __launch_bounds__(128) void pool_kernel(
    const float* __restrict__ x, const float* __restrict__ vals,
    const int* __restrict__ cols, const int* __restrict__ offsets,
    const int* __restrict__ perm, __hip_bfloat16* __restrict__ pool) {
    int r = blockIdx.x;
    int c = threadIdx.x;
    int j0 = offsets[r], j1 = offsets[r + 1];
    float acc[B_SZ];
#pragma unroll
    for (int b = 0; b < B_SZ; ++b) acc[b] = 0.f;
    for (int j = j0; j < j1; ++j) {
        int n = perm[j];
        float v = vals[n];
        const float* xp = x + (size_t)cols[n] * C_IN + c;
#pragma unroll
        for (int b = 0; b < B_SZ; ++b) acc[b] += v * xp[(size_t)b * V_IN * C_IN];
    }
#pragma unroll
    for (int b = 0; b < B_SZ; ++b)
        pool[((size_t)b * V_OUT + r) * C_IN + c] = __float2bfloat16(acc[b]);
}

// ---------------- combined weight (pre-swizzled per-K-tile LDS image) + bias ----------------
__global__ void wcomb_kernel(const float* __restrict__ W1, const float* __restrict__ Wd3,
                             const float* __restrict__ W2d3, const float* __restrict__ Wf,
                             const float* __restrict__ b1, const float* __restrict__ bd3,
                             const float* __restrict__ b2d3, const float* __restrict__ bf,
                             __hip_bfloat16* __restrict__ wTs, float* __restrict__ bias) {
    int idx = blockIdx.x * blockDim.x + threadIdx.x;
    if (idx >= NKT * 16384) {
        int c = idx - NKT * 16384;
        if (c < C_OUT) {
            float v = b1[c];
            if (c < 128)      v += bf[c];
            else if (c < 192) v += b2d3[c - 128];
            else              v += bd3[c - 192];
            bias[c] = v;
        }
        return;
    }
    int kt = idx >> 14;
    int c  = (idx >> 3) & 2047;
    int e  = idx & 7;
    int nrow  = c >> 3;
    int kslot = (c & 7) << 4;
    int kb = kslot ^ ((nrow & 7) << 4);
    int r  = kt * 64 + (kb >> 1) + e;    // global k, 0..2303
    int col = nrow;
    float v;
    if (col < 128)      v = Wf[r * 128 + col];
    else if (col < 192) v = (r < 1536) ? W2d3[r * 64 + (col - 128)] : 0.f;
    else                v = (r < 768)  ? Wd3[r * 64 + (col - 192)]  : 0.f;
    if (r < 128) v += W1[r * 256 + col];
    wTs[idx] = __float2bfloat16(v);
}

// ---------------- gathered GEMM: 256x256 tile, 16 waves, balanced K-skip ----------------
// Each wave (wm = 64-row band, wc = 0..3) owns column-tiles {2wc, 2wc+1, 8+wc, 12+wc}:
// 2 "full" tiles (36 K-tiles), 1 "mid" (24), 1 "short" (12) -> identical work per wave.
__global__ __launch_bounds__(1024, 4) void gemm_kernel(
    const __hip_bfloat16* __restrict__ pool,    // [16][4096][128] bf16
    const __hip_bfloat16* __restrict__ wTs,     // [36][16384] bf16, pre-swizzled K-tile images
    const float* __restrict__ bias,             // [256]
    const int* __restrict__ spiral,             // [4096][18]
    float* __restrict__ out)                    // [16][4096][256] f32
{
    // LDS: A slots @0,32768 ; B slots @65536,98304 ; spiral cache @131072 (18432B)
    __shared__ __align__(16) char smem[149504];
    int* spl = (int*)(smem + 131072);

    const int tid  = threadIdx.x;
    const int lane = tid & 63;
    const int wid  = tid >> 6;          // 0..15
    const int wc   = wid & 3;
    const int wm   = (wid >> 2) << 6;   // 0,64,128,192

    const int bid = blockIdx.x;
    const int bm  = ((bid & 7) << 5) + (bid >> 3);   // bijective XCD swizzle (256 = 8*32)
    const int b   = bm >> 4;                          // batch
    const int v0  = (bm & 15) << 8;                   // m-tile origin within batch

    // cache this block's spiral rows in LDS: 256 rows x 18
    for (int i = tid; i < 256 * K_NB; i += 1024) spl[i] = spiral[v0 * K_NB + i];
    asm volatile("s_waitcnt vmcnt(0) lgkmcnt(0)" ::: "memory");
    __builtin_amdgcn_s_barrier();

    const char* poolBytes = (const char*)(pool + (size_t)b * V_OUT * C_IN);
    const char* wTsBytes  = (const char*)wTs;
    // inverse-swizzled source column byte (identical for both 1024-chunks: (1024>>3)&7 == 0)
    const int sb = ((tid & 7) << 4) ^ (((tid >> 3) & 7) << 4);

    auto stageA = [&](int kt) {          // 2 vmem loads
        const int j   = kt >> 1;
        const int c0b = (kt & 1) << 7;
        char* dst = smem + ((kt & 1) << 15);
#pragma unroll
        for (int ch = 0; ch < 2; ++ch) {
            int flat = (ch << 10) + tid;
            int sidx = spl[(flat >> 3) * K_NB + j];
            GLOAD16(poolBytes + ((size_t)sidx << 8) + (c0b + sb), dst + flat * 16);
        }
    };
    auto stageB = [&](int kt) {          // 2 vmem loads
        const char* src = wTsBytes + ((size_t)kt << 15);
        char* dst = smem + 65536 + ((kt & 1) << 15);
#pragma unroll
        for (int ch = 0; ch < 2; ++ch) {
            int off = ((ch << 10) + tid) << 4;
            GLOAD16(src + off, dst + off);
        }
    };

    // per-lane fragment-read constants
    const int l15   = lane & 15;
    const int swm   = (lane & 7) << 4;          // frag-row&7 == lane&7
    const int klane = (lane >> 4) << 4;         // 0,16,32,48 (byte)
    const int aBase = (wm + l15) << 7;
    const int bOff0 = (((2 * wc)     << 4) + l15) << 7;   // full tile 0
    const int bOff1 = (((2 * wc + 1) << 4) + l15) << 7;   // full tile 1
    const int bOff2 = (((8 + wc)     << 4) + l15) << 7;   // mid tile
    const int bOff3 = (((12 + wc)    << 4) + l15) << 7;   // short tile

    f32x4 acc[4][4] = {};

    stageA(0);
    stageB(0);

    for (int kt = 0; kt < NKT; ++kt) {
        const int s = kt & 1;
        const char* As = smem + (s << 15);
        const char* Bs = smem + 65536 + (s << 15);

        if (kt + 1 < NKT) {
            stageA(kt + 1);
            asm volatile("s_waitcnt vmcnt(2)" ::: "memory");   // A(kt),B(kt) landed
        } else {
            asm volatile("s_waitcnt vmcnt(0)" ::: "memory");
        }
        __builtin_amdgcn_s_barrier();
        __builtin_amdgcn_sched_barrier(0);

        const bool doMid   = kt < 24;
        const bool doShort = kt < 12;

#pragma unroll
        for (int ks = 0; ks < 2; ++ks) {
            const int kk = (ks * 64 + klane) ^ swm;
            bf16x8 a0 = *(const bf16x8*)(As + aBase + (0 << 11) + kk);
            bf16x8 a1 = *(const bf16x8*)(As + aBase + (1 << 11) + kk);
            bf16x8 a2 = *(const bf16x8*)(As + aBase + (2 << 11) + kk);
            bf16x8 a3 = *(const bf16x8*)(As + aBase + (3 << 11) + kk);
            bf16x8 bb0 = *(const bf16x8*)(Bs + bOff0 + kk);
            bf16x8 bb1 = *(const bf16x8*)(Bs + bOff1 + kk);
            __builtin_amdgcn_s_setprio(1);
            acc[0][0] = __builtin_amdgcn_mfma_f32_16x16x32_bf16(a0, bb0, acc[0][0], 0, 0, 0);
            acc[1][0] = __builtin_amdgcn_mfma_f32_16x16x32_bf16(a1, bb0, acc[1][0], 0, 0, 0);
            acc[2][0] = __builtin_amdgcn_mfma_f32_16x16x32_bf16(a2, bb0, acc[2][0], 0, 0, 0);
            acc[3][0] = __builtin_amdgcn_mfma_f32_16x16x32_bf16(a3, bb0, acc[3][0], 0, 0, 0);
            acc[0][1] = __builtin_amdgcn_mfma_f32_16x16x32_bf16(a0, bb1, acc[0][1], 0, 0, 0);
            acc[1][1] = __builtin_amdgcn_mfma_f32_16x16x32_bf16(a1, bb1, acc[1][1], 0, 0, 0);
            acc[2][1] = __builtin_amdgcn_mfma_f32_16x16x32_bf16(a2, bb1, acc[2][1], 0, 0, 0);
            acc[3][1] = __builtin_amdgcn_mfma_f32_16x16x32_bf16(a3, bb1, acc[3][1], 0, 0, 0);
            __builtin_amdgcn_s_setprio(0);
            if (doMid) {
                bf16x8 bb2 = *(const bf16x8*)(Bs + bOff2 + kk);
                __builtin_amdgcn_s_setprio(1);
                acc[0][2] = __builtin_amdgcn_mfma_f32_16x16x32_bf16(a0, bb2, acc[0][2], 0, 0, 0);
                acc[1][2] = __builtin_amdgcn_mfma_f32_16x16x32_bf16(a1, bb2, acc[1][2], 0, 0, 0);
                acc[2][2] = __builtin_amdgcn_mfma_f32_16x16x32_bf16(a2, bb2, acc[2][2], 0, 0, 0);
                acc[3][2] = __builtin_amdgcn_mfma_f32_16x16x32_bf16(a3, bb2, acc[3][2], 0, 0, 0);
                __builtin_amdgcn_s_setprio(0);
            }
            if (doShort) {
                bf16x8 bb3 = *(const bf16x8*)(Bs + bOff3 + kk);
                __builtin_amdgcn_s_setprio(1);
                acc[0][3] = __builtin_amdgcn_mfma_f32_16x16x32_bf16(a0, bb3, acc[0][3], 0, 0, 0);
                acc[1][3] = __builtin_amdgcn_mfma_f32_16x16x32_bf16(a1, bb3, acc[1][3], 0, 0, 0);
                acc[2][3] = __builtin_amdgcn_mfma_f32_16x16x32_bf16(a2, bb3, acc[2][3], 0, 0, 0);
                acc[3][3] = __builtin_amdgcn_mfma_f32_16x16x32_bf16(a3, bb3, acc[3][3], 0, 0, 0);
                __builtin_amdgcn_s_setprio(0);
            }
            if (ks == 0 && kt + 1 < NKT) stageB(kt + 1);
        }

        __builtin_amdgcn_s_barrier();        // end of K-tile: slot reads complete
        __builtin_amdgcn_sched_barrier(0);
    }

    // epilogue: +bias, relu, store f32
    const int nt[4] = {2 * wc, 2 * wc + 1, 8 + wc, 12 + wc};
#pragma unroll
    for (int ni = 0; ni < 4; ++ni) {
        int col = (nt[ni] << 4) + l15;
        float bz = bias[col];
#pragma unroll
        for (int mi = 0; mi < 4; ++mi) {
            int row0 = v0 + wm + mi * 16 + ((lane >> 4) << 2);
#pragma unroll
            for (int r4 = 0; r4 < 4; ++r4) {
                float v = acc[mi][ni][r4] + bz;
                out[((size_t)(b * V_OUT + row0 + r4)) * C_OUT + col] = v > 0.f ? v : 0.f;
            }
        }
    }
}

extern "C" void kernel_launch(void* const* d_in, const int* in_sizes, int n_in,
                              void* d_out, int out_size, void* d_ws, size_t ws_size,
                              hipStream_t stream) {
    const float* x     = (const float*)d_in[0];
    const float* vals  = (const float*)d_in[1];
    const float* W1    = (const float*)d_in[2];
    const float* b1    = (const float*)d_in[3];
    const float* Wd3   = (const float*)d_in[4];
    const float* bd3   = (const float*)d_in[5];
    const float* W2d3  = (const float*)d_in[6];
    const float* b2d3  = (const float*)d_in[7];
    const float* Wf    = (const float*)d_in[8];
    const float* bf    = (const float*)d_in[9];
    const int*   rows  = (const int*)d_in[10];
    const int*   cols  = (const int*)d_in[11];
    const int*   spiral= (const int*)d_in[12];
    float* out = (float*)d_out;

    // workspace layout
    char* ws = (char*)d_ws;
    __hip_bfloat16* pool = (__hip_bfloat16*)ws;                              // 16,777,216 B
    __hip_bfloat16* wTs  = (__hip_bfloat16*)(ws + 16777216);                 //  1,179,648 B
    float* bias          = (float*)(ws + 16777216 + 1179648);                //      1,024 B
    int*   counts        = (int*)(ws + 16777216 + 1179648 + 1024);
    int*   offsets       = counts + V_OUT;          // V_OUT+1 ints
    int*   cursor        = offsets + V_OUT + 4;     // padded
    int*   perm          = cursor + V_OUT;

    hipMemsetAsync(counts, 0, V_OUT * sizeof(int), stream);
    hist_kernel<<<NNZ / 256, 256, 0, stream>>>(rows, counts);
    scan_kernel<<<1, 1024, 0, stream>>>(counts, offsets, cursor);
    fill_kernel<<<NNZ / 256, 256, 0, stream>>>(rows, cursor, perm);
    pool_kernel<<<V_OUT, C_IN, 0, stream>>>(x, vals, cols, offsets, perm, pool);
    wcomb_kernel<<<(NKT * 16384 + C_OUT + 255) / 256, 256, 0, stream>>>(
        W1, Wd3, W2d3, Wf, b1, bd3, b2d3, bf, wTs, bias);
    gemm_kernel<<<256, 1024, 0, stream>>>(pool, wTs, bias, spiral, out);
}